// Round 4
// baseline (602.694 us; speedup 1.0000x reference)
//
#include <hip/hip_runtime.h>

#define RESV 32
#define R3V (RESV * RESV * RESV)

// ============================ common small kernels ============================

__global__ void k_sums(const float* __restrict__ coords, float* __restrict__ ws_sums, int N) {
    const int b = blockIdx.y;
    const float* cb = coords + (size_t)b * 3 * N;
    float sx = 0.f, sy = 0.f, sz = 0.f;
    for (int n = blockIdx.x * blockDim.x + threadIdx.x; n < N; n += gridDim.x * blockDim.x) {
        sx += cb[n];
        sy += cb[N + n];
        sz += cb[2 * N + n];
    }
    for (int off = 32; off > 0; off >>= 1) {
        sx += __shfl_down(sx, off);
        sy += __shfl_down(sy, off);
        sz += __shfl_down(sz, off);
    }
    __shared__ float red[3][4];
    const int lane = threadIdx.x & 63;
    const int wv   = threadIdx.x >> 6;
    if (lane == 0) { red[0][wv] = sx; red[1][wv] = sy; red[2][wv] = sz; }
    __syncthreads();
    if (threadIdx.x == 0) {
        float tx = 0.f, ty = 0.f, tz = 0.f;
        const int nw = blockDim.x >> 6;
        for (int w = 0; w < nw; ++w) { tx += red[0][w]; ty += red[1][w]; tz += red[2][w]; }
        atomicAdd(&ws_sums[b * 3 + 0], tx);
        atomicAdd(&ws_sums[b * 3 + 1], ty);
        atomicAdd(&ws_sums[b * 3 + 2], tz);
    }
}

__global__ void k_maxrad(const float* __restrict__ coords, const float* __restrict__ ws_sums,
                         unsigned int* __restrict__ ws_max, int N) {
    const int b = blockIdx.y;
    const float invN = 1.0f / (float)N;
    const float mx = ws_sums[b * 3 + 0] * invN;
    const float my = ws_sums[b * 3 + 1] * invN;
    const float mz = ws_sums[b * 3 + 2] * invN;
    const float* cb = coords + (size_t)b * 3 * N;
    float r = 0.f;
    for (int n = blockIdx.x * blockDim.x + threadIdx.x; n < N; n += gridDim.x * blockDim.x) {
        const float dx = cb[n] - mx;
        const float dy = cb[N + n] - my;
        const float dz = cb[2 * N + n] - mz;
        r = fmaxf(r, sqrtf(dx * dx + dy * dy + dz * dz));
    }
    for (int off = 32; off > 0; off >>= 1) r = fmaxf(r, __shfl_down(r, off));
    __shared__ float red[4];
    const int lane = threadIdx.x & 63;
    const int wv   = threadIdx.x >> 6;
    if (lane == 0) red[wv] = r;
    __syncthreads();
    if (threadIdx.x == 0) {
        const int nw = blockDim.x >> 6;
        float t = 0.f;
        for (int w = 0; w < nw; ++w) t = fmaxf(t, red[w]);
        atomicMax(&ws_max[b], __float_as_uint(t));
    }
}

// norm coords + voxel idx + per-voxel counts (global int atomics, ~800K total)
__global__ void k_points(const float* __restrict__ coords, const float* __restrict__ ws_sums,
                         const unsigned int* __restrict__ ws_max,
                         float* __restrict__ norm_out, int* __restrict__ idx_ws,
                         int* __restrict__ counts, int N) {
    const int b = blockIdx.y;
    const int n = blockIdx.x * blockDim.x + threadIdx.x;
    if (n >= N) return;
    const float invN  = 1.0f / (float)N;
    const float scale = 2.0f * __uint_as_float(ws_max[b]);
    const float* cb = coords + (size_t)b * 3 * N;
    float* nb = norm_out + (size_t)b * 3 * N;

    int flat = 0;
#pragma unroll
    for (int d = 0; d < 3; ++d) {
        const float mean = ws_sums[b * 3 + d] * invN;
        float nc = (cb[d * N + n] - mean) / scale + 0.5f;
        nc = fminf(fmaxf(nc * (float)RESV, 0.0f), (float)(RESV - 1));
        nb[d * N + n] = nc;
        flat = flat * RESV + (int)rintf(nc);
    }
    idx_ws[(size_t)b * N + n] = flat;
    atomicAdd(&counts[b * R3V + flat], 1);
}

// ============================ CSR pipeline ============================

// Per-batch exclusive scan of 32768 counts -> start, cursor; recip = 1/max(cnt,1)
__global__ __launch_bounds__(1024, 1) void k_scan(const int* __restrict__ counts,
                                                  int* __restrict__ start,
                                                  int* __restrict__ cursor,
                                                  float* __restrict__ recip) {
    const int b = blockIdx.x;
    const int t = threadIdx.x;
    const int base = b * R3V + t * 32;
    int c[32];
    int T = 0;
#pragma unroll
    for (int i = 0; i < 32; ++i) { c[i] = counts[base + i]; T += c[i]; }
    // 64-lane inclusive scan of T
    int incl = T;
    const int lane = t & 63;
    for (int off = 1; off < 64; off <<= 1) {
        int y = __shfl_up(incl, off);
        if (lane >= off) incl += y;
    }
    __shared__ int wsum[16];
    __shared__ int wbase[16];
    const int w = t >> 6;
    if (lane == 63) wsum[w] = incl;
    __syncthreads();
    if (t == 0) {
        int run = 0;
        for (int i = 0; i < 16; ++i) { wbase[i] = run; run += wsum[i]; }
    }
    __syncthreads();
    int run = wbase[w] + incl - T;  // exclusive prefix for this thread's chunk
#pragma unroll
    for (int i = 0; i < 32; ++i) {
        start[base + i]  = run;
        cursor[base + i] = run;
        recip[base + i]  = 1.0f / fmaxf((float)c[i], 1.0f);
        run += c[i];
    }
}

// perm[j] = n for each point, j = rank within its voxel (CSR column indices)
__global__ void k_rank(const int* __restrict__ idx_ws, int* __restrict__ cursor,
                       int* __restrict__ perm, int N) {
    const int b = blockIdx.y;
    const int n = blockIdx.x * blockDim.x + threadIdx.x;
    if (n >= N) return;
    const int v = idx_ws[(size_t)b * N + n];
    const int j = atomicAdd(&cursor[b * R3V + v], 1);
    perm[(size_t)b * N + j] = n;
}

// feats [B,C=64,N] -> featsT [B,N,64] via padded LDS tile; both sides coalesced
__global__ __launch_bounds__(1024, 2) void k_transpose(const float* __restrict__ feats,
                                                       float* __restrict__ featsT, int N) {
    __shared__ float tile[64][257];
    const int b  = blockIdx.y;
    const int n0 = blockIdx.x * 256;
    const int t  = threadIdx.x;
    const int nn = t & 255;
    const int c0 = t >> 8;  // 0..3
    const float* fb = feats + (size_t)b * 64 * N;
#pragma unroll
    for (int k = 0; k < 16; ++k) {
        const int cc = c0 + k * 4;
        const int n  = n0 + nn;
        tile[cc][nn] = (n < N) ? fb[(size_t)cc * N + n] : 0.f;
    }
    __syncthreads();
    const int wv   = t >> 6;  // 0..15
    const int lane = t & 63;  // channel
#pragma unroll
    for (int pass = 0; pass < 16; ++pass) {
        const int p = wv + pass * 16;  // 0..255
        const int n = n0 + p;
        if (n < N) featsT[((size_t)b * N + n) * 64 + lane] = tile[lane][p];
    }
}

// Gather: block = (b, 32-voxel column). Wave = one voxel at a time, lane = channel.
// Per point: one coalesced 256B read of featsT[p][:]; register accumulation; no atomics.
__global__ __launch_bounds__(256, 4) void k_gather(const float* __restrict__ featsT,
                                                   const int* __restrict__ perm,
                                                   const int* __restrict__ startv,
                                                   const float* __restrict__ recip,
                                                   float* __restrict__ grid, int N) {
    __shared__ float outl[64][33];
    const int b    = blockIdx.y;
    const int v0   = blockIdx.x * 32;
    const int t    = threadIdx.x;
    const int wv   = t >> 6;  // 0..3
    const int lane = t & 63;  // channel
    const int*   pm = perm   + (size_t)b * N;
    const float* fT = featsT + (size_t)b * N * 64;
    const int*   sv = startv + b * R3V;
    const float* rc = recip  + b * R3V;
#pragma unroll
    for (int q = 0; q < 8; ++q) {
        const int vl = wv + q * 4;  // 0..31
        const int v  = v0 + vl;
        const int s  = sv[v];
        const int e  = (v == R3V - 1) ? N : sv[v + 1];
        float sum = 0.f;
        int j = s;
        for (; j + 1 < e; j += 2) {
            const int p0 = pm[j], p1 = pm[j + 1];
            sum += fT[(size_t)p0 * 64 + lane] + fT[(size_t)p1 * 64 + lane];
        }
        if (j < e) sum += fT[(size_t)pm[j] * 64 + lane];
        outl[lane][vl] = sum * rc[v];
    }
    __syncthreads();
    const int vl = t & 31;
    const int cq = t >> 5;  // 0..7
    float* gb = grid + (size_t)b * 64 * R3V;
#pragma unroll
    for (int k = 0; k < 8; ++k) {
        const int cc = cq + k * 8;
        gb[(size_t)cc * R3V + v0 + vl] = outl[cc][vl];
    }
}

// ============================ fallback (small ws): R2 scatter ============================

__device__ __forceinline__ int swz(int v) {
    return v ^ ((v >> 5) & 31) ^ ((v >> 10) & 31);
}

__global__ void k_recip_fb(const int* __restrict__ cnt, float* __restrict__ recip, int total) {
    const int i = blockIdx.x * blockDim.x + threadIdx.x;
    if (i < total) recip[i] = 1.0f / fmaxf((float)cnt[i], 1.0f);
}

__global__ __launch_bounds__(1024, 1) void k_scatter_lds(
        const float* __restrict__ feats, const int* __restrict__ idx_ws,
        const float* __restrict__ recip, float* __restrict__ grid, int N, int C) {
    extern __shared__ float acc[];
    const int bc  = blockIdx.x;
    const int b   = bc / C;
    const int tid = threadIdx.x;
    for (int i = tid * 4; i < R3V; i += blockDim.x * 4)
        *(float4*)(acc + i) = make_float4(0.f, 0.f, 0.f, 0.f);
    __syncthreads();
    const float* fb = feats  + (size_t)bc * N;
    const int*   ib = idx_ws + (size_t)b  * N;
    const int n4 = (N / 4) * 4;
    for (int n = tid * 4; n < n4; n += blockDim.x * 4) {
        const float4 f = *(const float4*)(fb + n);
        const int4  ix = *(const int4*)(ib + n);
        atomicAdd(&acc[swz(ix.x)], f.x);
        atomicAdd(&acc[swz(ix.y)], f.y);
        atomicAdd(&acc[swz(ix.z)], f.z);
        atomicAdd(&acc[swz(ix.w)], f.w);
    }
    for (int n = n4 + tid; n < N; n += blockDim.x) atomicAdd(&acc[swz(ib[n])], fb[n]);
    __syncthreads();
    const float* rb = recip + (size_t)b * R3V;
    float*       gb = grid  + (size_t)bc * R3V;
    for (int i = tid; i < R3V; i += blockDim.x)
        gb[i] = acc[swz(i)] * rb[i];
}

// ============================ launch ============================

extern "C" void kernel_launch(void* const* d_in, const int* in_sizes, int n_in,
                              void* d_out, int out_size, void* d_ws, size_t ws_size,
                              hipStream_t stream) {
    const float* feats  = (const float*)d_in[0];
    const float* coords = (const float*)d_in[1];

    const long long s0 = in_sizes[0], s1 = in_sizes[1];
    const int BC = (int)(((long long)out_size - s1) / R3V);  // B*C
    const int N  = (int)(s0 / BC);
    const int B  = (int)(s1 / (3LL * N));
    const int C  = BC / B;

    float* out_grid = (float*)d_out;               // [B, C, R3]
    float* out_norm = out_grid + (size_t)BC * R3V; // [B, 3, N]

    // ws layout (in floats/int32 slots):
    // [0,64)            header: sums (3B) at 0, max bits (B) at 32
    // [64, +BR3)        counts (int)
    // [.., +BR3)        start  (int)
    // [.., +BR3)        cursor (int)
    // [.., +BR3)        recip  (float)
    // [.., +BN)         idx    (int)
    // [.., +BN)         perm   (int)
    // [aligned 64, +B*N*64) featsT (float)
    const size_t BR3 = (size_t)B * R3V;
    const size_t BN  = (size_t)B * N;
    const size_t o_counts = 64;
    const size_t o_start  = o_counts + BR3;
    const size_t o_cursor = o_start + BR3;
    const size_t o_recip  = o_cursor + BR3;
    const size_t o_idx    = o_recip + BR3;
    const size_t o_perm   = o_idx + BN;
    size_t o_fT = o_perm + BN;
    o_fT = (o_fT + 63) & ~(size_t)63;
    const size_t need = (o_fT + BN * 64) * sizeof(float);

    float*        ws_sums = (float*)d_ws;
    unsigned int* ws_max  = (unsigned int*)((float*)d_ws + 32);
    int*          counts  = (int*)d_ws + o_counts;
    int*          startv  = (int*)d_ws + o_start;
    int*          cursor  = (int*)d_ws + o_cursor;
    float*        recip   = (float*)d_ws + o_recip;
    int*          idx_ws  = (int*)d_ws + o_idx;
    int*          perm    = (int*)d_ws + o_perm;
    float*        featsT  = (float*)d_ws + o_fT;

    // zero header + counts (contiguous)
    hipMemsetAsync(d_ws, 0, (64 + BR3) * sizeof(float), stream);

    const int BLK = 256;
    dim3 gRed(32, B);
    k_sums<<<gRed, BLK, 0, stream>>>(coords, ws_sums, N);
    k_maxrad<<<gRed, BLK, 0, stream>>>(coords, ws_sums, ws_max, N);

    dim3 gPts((N + BLK - 1) / BLK, B);
    k_points<<<gPts, BLK, 0, stream>>>(coords, ws_sums, ws_max, out_norm, idx_ws, counts, N);

    if (ws_size >= need && C == 64) {
        // CSR + transpose + gather path (no hot-loop atomics)
        k_scan<<<dim3(B), 1024, 0, stream>>>(counts, startv, cursor, recip);
        k_rank<<<gPts, BLK, 0, stream>>>(idx_ws, cursor, perm, N);
        dim3 gT((N + 255) / 256, B);
        k_transpose<<<gT, 1024, 0, stream>>>(feats, featsT, N);
        dim3 gG(R3V / 32, B);
        k_gather<<<gG, 256, 0, stream>>>(featsT, perm, startv, recip, out_grid, N);
    } else {
        // fallback: LDS-atomic scatter (R2)
        const int tot = B * R3V;
        k_recip_fb<<<(tot + BLK - 1) / BLK, BLK, 0, stream>>>(counts, recip, tot);
        k_scatter_lds<<<dim3(BC), 1024, R3V * sizeof(float), stream>>>(
            feats, idx_ws, recip, out_grid, N, C);
    }
}

// Round 5
// 438.146 us; speedup vs baseline: 1.3756x; 1.3756x over previous
//
#include <hip/hip_runtime.h>
#include <hip/hip_bf16.h>

#define RESV 32
#define R3V (RESV * RESV * RESV)
#define R3P1 (R3V + 1)
#define CH 256  // sorted points per wave-chunk in k_gather3

// ============================ small prep kernels ============================

__global__ void k_sums(const float* __restrict__ coords, float* __restrict__ ws_sums, int N) {
    const int b = blockIdx.y;
    const float* cb = coords + (size_t)b * 3 * N;
    float sx = 0.f, sy = 0.f, sz = 0.f;
    for (int n = blockIdx.x * blockDim.x + threadIdx.x; n < N; n += gridDim.x * blockDim.x) {
        sx += cb[n];
        sy += cb[N + n];
        sz += cb[2 * N + n];
    }
    for (int off = 32; off > 0; off >>= 1) {
        sx += __shfl_down(sx, off);
        sy += __shfl_down(sy, off);
        sz += __shfl_down(sz, off);
    }
    __shared__ float red[3][4];
    const int lane = threadIdx.x & 63;
    const int wv   = threadIdx.x >> 6;
    if (lane == 0) { red[0][wv] = sx; red[1][wv] = sy; red[2][wv] = sz; }
    __syncthreads();
    if (threadIdx.x == 0) {
        float tx = 0.f, ty = 0.f, tz = 0.f;
        const int nw = blockDim.x >> 6;
        for (int w = 0; w < nw; ++w) { tx += red[0][w]; ty += red[1][w]; tz += red[2][w]; }
        atomicAdd(&ws_sums[b * 3 + 0], tx);
        atomicAdd(&ws_sums[b * 3 + 1], ty);
        atomicAdd(&ws_sums[b * 3 + 2], tz);
    }
}

__global__ void k_maxrad(const float* __restrict__ coords, const float* __restrict__ ws_sums,
                         unsigned int* __restrict__ ws_max, int N) {
    const int b = blockIdx.y;
    const float invN = 1.0f / (float)N;
    const float mx = ws_sums[b * 3 + 0] * invN;
    const float my = ws_sums[b * 3 + 1] * invN;
    const float mz = ws_sums[b * 3 + 2] * invN;
    const float* cb = coords + (size_t)b * 3 * N;
    float r = 0.f;
    for (int n = blockIdx.x * blockDim.x + threadIdx.x; n < N; n += gridDim.x * blockDim.x) {
        const float dx = cb[n] - mx;
        const float dy = cb[N + n] - my;
        const float dz = cb[2 * N + n] - mz;
        r = fmaxf(r, sqrtf(dx * dx + dy * dy + dz * dz));
    }
    for (int off = 32; off > 0; off >>= 1) r = fmaxf(r, __shfl_down(r, off));
    __shared__ float red[4];
    const int lane = threadIdx.x & 63;
    const int wv   = threadIdx.x >> 6;
    if (lane == 0) red[wv] = r;
    __syncthreads();
    if (threadIdx.x == 0) {
        const int nw = blockDim.x >> 6;
        float t = 0.f;
        for (int w = 0; w < nw; ++w) t = fmaxf(t, red[w]);
        atomicMax(&ws_max[b], __float_as_uint(t));
    }
}

// norm coords + voxel idx + per-voxel counts
__global__ void k_points(const float* __restrict__ coords, const float* __restrict__ ws_sums,
                         const unsigned int* __restrict__ ws_max,
                         float* __restrict__ norm_out, int* __restrict__ idx_ws,
                         int* __restrict__ counts, int N) {
    const int b = blockIdx.y;
    const int n = blockIdx.x * blockDim.x + threadIdx.x;
    if (n >= N) return;
    const float invN  = 1.0f / (float)N;
    const float scale = 2.0f * __uint_as_float(ws_max[b]);
    const float* cb = coords + (size_t)b * 3 * N;
    float* nb = norm_out + (size_t)b * 3 * N;

    int flat = 0;
#pragma unroll
    for (int d = 0; d < 3; ++d) {
        const float mean = ws_sums[b * 3 + d] * invN;
        float nc = (cb[d * N + n] - mean) / scale + 0.5f;
        nc = fminf(fmaxf(nc * (float)RESV, 0.0f), (float)(RESV - 1));
        nb[d * N + n] = nc;
        flat = flat * RESV + (int)rintf(nc);
    }
    idx_ws[(size_t)b * N + n] = flat;
    atomicAdd(&counts[b * R3V + flat], 1);
}

// Per-batch exclusive scan of counts -> start (stride R3P1, sentinel start[R3V]=N),
// cursor (stride R3V), recip = 1/max(cnt,1)
__global__ __launch_bounds__(1024, 1) void k_scan(const int* __restrict__ counts,
                                                  int* __restrict__ start,
                                                  int* __restrict__ cursor,
                                                  float* __restrict__ recip, int N) {
    const int b = blockIdx.x;
    const int t = threadIdx.x;
    const int base  = b * R3V + t * 32;
    const int baseS = b * R3P1 + t * 32;
    int c[32];
    int T = 0;
#pragma unroll
    for (int i = 0; i < 32; ++i) { c[i] = counts[base + i]; T += c[i]; }
    int incl = T;
    const int lane = t & 63;
    for (int off = 1; off < 64; off <<= 1) {
        int y = __shfl_up(incl, off);
        if (lane >= off) incl += y;
    }
    __shared__ int wsum[16];
    __shared__ int wbase[16];
    const int w = t >> 6;
    if (lane == 63) wsum[w] = incl;
    __syncthreads();
    if (t == 0) {
        int run = 0;
        for (int i = 0; i < 16; ++i) { wbase[i] = run; run += wsum[i]; }
    }
    __syncthreads();
    int run = wbase[w] + incl - T;  // exclusive prefix
#pragma unroll
    for (int i = 0; i < 32; ++i) {
        start[baseS + i] = run;
        cursor[base + i] = run;
        recip[base + i]  = 1.0f / fmaxf((float)c[i], 1.0f);
        run += c[i];
    }
    if (t == 1023) start[b * R3P1 + R3V] = run;  // == N
}

// feats [B,64,N] -> fTs [B,N,64] bf16, rows written in SORTED (voxel) order.
// Rank assignment fused: j = atomicAdd(cursor[v]); also records voxid[j]=v.
__global__ __launch_bounds__(1024, 2) void k_transpose_perm(
        const float* __restrict__ feats, const int* __restrict__ idx_ws,
        int* __restrict__ cursor, __hip_bfloat16* __restrict__ fTs,
        int* __restrict__ voxid, int N) {
    __shared__ float tile[64][257];
    __shared__ int jrow[256];
    const int b  = blockIdx.y;
    const int n0 = blockIdx.x * 256;
    const int t  = threadIdx.x;
    const int nn = t & 255;
    const int c0 = t >> 8;  // 0..3
    const float* fb = feats + (size_t)b * 64 * N;
#pragma unroll
    for (int k = 0; k < 16; ++k) {
        const int cc = c0 + k * 4;
        const int n  = n0 + nn;
        tile[cc][nn] = (n < N) ? fb[(size_t)cc * N + n] : 0.f;
    }
    if (t < 256) {
        const int n = n0 + t;
        if (n < N) {
            const int v = idx_ws[(size_t)b * N + n];
            const int j = atomicAdd(&cursor[b * R3V + v], 1);
            jrow[t] = j;
            voxid[(size_t)b * N + j] = v;
        }
    }
    __syncthreads();
    const int wv   = t >> 6;  // 0..15
    const int lane = t & 63;  // channel
    __hip_bfloat16* fo = fTs + (size_t)b * N * 64;
#pragma unroll
    for (int pass = 0; pass < 16; ++pass) {
        const int p = wv + pass * 16;  // 0..255
        if (n0 + p < N) {
            const int row = jrow[p];
            fo[(size_t)row * 64 + lane] = __float2bfloat16(tile[lane][p]);
        }
    }
}

// Chunk-balanced segmented reduction over sorted rows.
// wave = CH consecutive sorted points; lane = channel; register accumulate;
// flush per segment to gridT[b][v][c] (coalesced 256B): plain store if the
// segment lies entirely inside this chunk, else atomicAdd (<=2 per chunk).
__global__ void k_gather3(const __hip_bfloat16* __restrict__ fTs,
                          const int* __restrict__ voxid,
                          const int* __restrict__ startv,
                          float* __restrict__ gridT, int N, int nchunk) {
    const int w     = threadIdx.x >> 6;
    const int lane  = threadIdx.x & 63;
    const int chunk = blockIdx.x * 4 + w;
    if (chunk >= nchunk) return;
    const int b  = blockIdx.y;
    const int c0 = chunk * CH;
    const int end = min(c0 + CH, N);
    const __hip_bfloat16* fb = fTs + (size_t)b * N * 64;
    const int* vi = voxid  + (size_t)b * N;
    const int* sv = startv + (size_t)b * R3P1;
    float* gT = gridT + (size_t)b * R3V * 64;

    int j = c0;
    while (j < end) {
        const int v = vi[j];             // wave-uniform broadcast load
        const int s = sv[v];
        const int e = sv[v + 1];         // sentinel makes v+1 always valid
        const int segEnd = min(e, end);
        float acc = 0.f;
        for (; j + 4 <= segEnd; j += 4) {
            const float a0 = __bfloat162float(fb[(size_t)(j + 0) * 64 + lane]);
            const float a1 = __bfloat162float(fb[(size_t)(j + 1) * 64 + lane]);
            const float a2 = __bfloat162float(fb[(size_t)(j + 2) * 64 + lane]);
            const float a3 = __bfloat162float(fb[(size_t)(j + 3) * 64 + lane]);
            acc += (a0 + a1) + (a2 + a3);
        }
        for (; j < segEnd; ++j) acc += __bfloat162float(fb[(size_t)j * 64 + lane]);
        float* dst = gT + (size_t)v * 64 + lane;
        if (s >= c0 && e <= end) *dst = acc;      // segment interior to chunk
        else atomicAdd(dst, acc);                 // chunk-boundary segment
    }
}

// gridT [B,R3,64] -> grid [B,64,R3], fused with *recip. Writes every element.
__global__ __launch_bounds__(256) void k_fin(const float* __restrict__ gridT,
                                             const float* __restrict__ recip,
                                             float* __restrict__ grid) {
    __shared__ float tile[64][65];
    const int b    = blockIdx.y;
    const int v0   = blockIdx.x * 64;
    const int t    = threadIdx.x;
    const int lane = t & 63;
    const int w    = t >> 6;  // 0..3
    const float* gT = gridT + ((size_t)b * R3V + v0) * 64;
#pragma unroll
    for (int k = 0; k < 16; ++k) {
        const int r = w + k * 4;
        tile[r][lane] = gT[(size_t)r * 64 + lane];
    }
    __syncthreads();
    const float rc = recip[(size_t)b * R3V + v0 + lane];
    float* gb = grid + (size_t)b * 64 * R3V;
#pragma unroll
    for (int k = 0; k < 16; ++k) {
        const int c = w + k * 4;
        gb[(size_t)c * R3V + v0 + lane] = tile[lane][c] * rc;
    }
}

// ============================ fallback: R2 LDS-atomic scatter ============================

__device__ __forceinline__ int swz(int v) {
    return v ^ ((v >> 5) & 31) ^ ((v >> 10) & 31);
}

__global__ void k_recip_fb(const int* __restrict__ cnt, float* __restrict__ recip, int total) {
    const int i = blockIdx.x * blockDim.x + threadIdx.x;
    if (i < total) recip[i] = 1.0f / fmaxf((float)cnt[i], 1.0f);
}

__global__ __launch_bounds__(1024, 1) void k_scatter_lds(
        const float* __restrict__ feats, const int* __restrict__ idx_ws,
        const float* __restrict__ recip, float* __restrict__ grid, int N, int C) {
    extern __shared__ float acc[];
    const int bc  = blockIdx.x;
    const int b   = bc / C;
    const int tid = threadIdx.x;
    for (int i = tid * 4; i < R3V; i += blockDim.x * 4)
        *(float4*)(acc + i) = make_float4(0.f, 0.f, 0.f, 0.f);
    __syncthreads();
    const float* fb = feats  + (size_t)bc * N;
    const int*   ib = idx_ws + (size_t)b  * N;
    const int n4 = (N / 4) * 4;
    for (int n = tid * 4; n < n4; n += blockDim.x * 4) {
        const float4 f = *(const float4*)(fb + n);
        const int4  ix = *(const int4*)(ib + n);
        atomicAdd(&acc[swz(ix.x)], f.x);
        atomicAdd(&acc[swz(ix.y)], f.y);
        atomicAdd(&acc[swz(ix.z)], f.z);
        atomicAdd(&acc[swz(ix.w)], f.w);
    }
    for (int n = n4 + tid; n < N; n += blockDim.x) atomicAdd(&acc[swz(ib[n])], fb[n]);
    __syncthreads();
    const float* rb = recip + (size_t)b * R3V;
    float*       gb = grid  + (size_t)bc * R3V;
    for (int i = tid; i < R3V; i += blockDim.x)
        gb[i] = acc[swz(i)] * rb[i];
}

// ============================ launch ============================

extern "C" void kernel_launch(void* const* d_in, const int* in_sizes, int n_in,
                              void* d_out, int out_size, void* d_ws, size_t ws_size,
                              hipStream_t stream) {
    const float* feats  = (const float*)d_in[0];
    const float* coords = (const float*)d_in[1];

    const long long s0 = in_sizes[0], s1 = in_sizes[1];
    const int BC = (int)(((long long)out_size - s1) / R3V);  // B*C
    const int N  = (int)(s0 / BC);
    const int B  = (int)(s1 / (3LL * N));
    const int C  = BC / B;

    float* out_grid = (float*)d_out;               // [B, C, R3]
    float* out_norm = out_grid + (size_t)BC * R3V; // [B, 3, N]

    // ws layout (float32 slots)
    const size_t BR3 = (size_t)B * R3V;
    const size_t BN  = (size_t)B * N;
    const size_t o_counts = 64;
    const size_t o_start  = o_counts + BR3;
    const size_t o_cursor = o_start + (size_t)B * R3P1;
    const size_t o_recip  = o_cursor + BR3;
    const size_t o_idx    = o_recip + BR3;
    const size_t o_voxid  = o_idx + BN;
    size_t o_gridT = (o_voxid + BN + 63) & ~(size_t)63;
    size_t o_fTs   = (o_gridT + BR3 * 64 + 63) & ~(size_t)63;
    const size_t need = (o_fTs + (BN * 64 + 1) / 2) * sizeof(float);  // fTs is bf16

    float*        ws_sums = (float*)d_ws;
    unsigned int* ws_max  = (unsigned int*)((float*)d_ws + 32);
    int*          counts  = (int*)d_ws + o_counts;
    int*          startv  = (int*)d_ws + o_start;
    int*          cursor  = (int*)d_ws + o_cursor;
    float*        recip   = (float*)d_ws + o_recip;
    int*          idx_ws  = (int*)d_ws + o_idx;
    int*          voxid   = (int*)d_ws + o_voxid;
    float*        gridT   = (float*)d_ws + o_gridT;
    __hip_bfloat16* fTs   = (__hip_bfloat16*)((float*)d_ws + o_fTs);

    // zero header + counts (contiguous)
    hipMemsetAsync(d_ws, 0, (64 + BR3) * sizeof(float), stream);

    const int BLK = 256;
    dim3 gRed(32, B);
    k_sums<<<gRed, BLK, 0, stream>>>(coords, ws_sums, N);
    k_maxrad<<<gRed, BLK, 0, stream>>>(coords, ws_sums, ws_max, N);

    dim3 gPts((N + BLK - 1) / BLK, B);
    k_points<<<gPts, BLK, 0, stream>>>(coords, ws_sums, ws_max, out_norm, idx_ws, counts, N);

    if (ws_size >= need && C == 64) {
        hipMemsetAsync(gridT, 0, BR3 * 64 * sizeof(float), stream);
        k_scan<<<dim3(B), 1024, 0, stream>>>(counts, startv, cursor, recip, N);
        dim3 gT((N + 255) / 256, B);
        k_transpose_perm<<<gT, 1024, 0, stream>>>(feats, idx_ws, cursor, fTs, voxid, N);
        const int nchunk = (N + CH - 1) / CH;
        dim3 gG((nchunk + 3) / 4, B);
        k_gather3<<<gG, 256, 0, stream>>>(fTs, voxid, startv, gridT, N, nchunk);
        dim3 gF(R3V / 64, B);
        k_fin<<<gF, 256, 0, stream>>>(gridT, recip, out_grid);
    } else {
        const int tot = B * R3V;
        k_recip_fb<<<(tot + BLK - 1) / BLK, BLK, 0, stream>>>(counts, recip, tot);
        k_scatter_lds<<<dim3(BC), 1024, R3V * sizeof(float), stream>>>(
            feats, idx_ws, recip, out_grid, N, C);
    }
}

// Round 6
// 270.585 us; speedup vs baseline: 2.2274x; 1.6193x over previous
//
#include <hip/hip_runtime.h>
#include <hip/hip_bf16.h>

#define RESV 32
#define R3V (RESV * RESV * RESV)
#define R3P1 (R3V + 1)
#define CH 64  // sorted points per wave-chunk in k_gather4

// ============================ small prep kernels ============================

__global__ void k_sums(const float* __restrict__ coords, float* __restrict__ ws_sums, int N) {
    const int b = blockIdx.y;
    const float* cb = coords + (size_t)b * 3 * N;
    float sx = 0.f, sy = 0.f, sz = 0.f;
    for (int n = blockIdx.x * blockDim.x + threadIdx.x; n < N; n += gridDim.x * blockDim.x) {
        sx += cb[n];
        sy += cb[N + n];
        sz += cb[2 * N + n];
    }
    for (int off = 32; off > 0; off >>= 1) {
        sx += __shfl_down(sx, off);
        sy += __shfl_down(sy, off);
        sz += __shfl_down(sz, off);
    }
    __shared__ float red[3][4];
    const int lane = threadIdx.x & 63;
    const int wv   = threadIdx.x >> 6;
    if (lane == 0) { red[0][wv] = sx; red[1][wv] = sy; red[2][wv] = sz; }
    __syncthreads();
    if (threadIdx.x == 0) {
        float tx = 0.f, ty = 0.f, tz = 0.f;
        const int nw = blockDim.x >> 6;
        for (int w = 0; w < nw; ++w) { tx += red[0][w]; ty += red[1][w]; tz += red[2][w]; }
        atomicAdd(&ws_sums[b * 3 + 0], tx);
        atomicAdd(&ws_sums[b * 3 + 1], ty);
        atomicAdd(&ws_sums[b * 3 + 2], tz);
    }
}

__global__ void k_maxrad(const float* __restrict__ coords, const float* __restrict__ ws_sums,
                         unsigned int* __restrict__ ws_max, int N) {
    const int b = blockIdx.y;
    const float invN = 1.0f / (float)N;
    const float mx = ws_sums[b * 3 + 0] * invN;
    const float my = ws_sums[b * 3 + 1] * invN;
    const float mz = ws_sums[b * 3 + 2] * invN;
    const float* cb = coords + (size_t)b * 3 * N;
    float r = 0.f;
    for (int n = blockIdx.x * blockDim.x + threadIdx.x; n < N; n += gridDim.x * blockDim.x) {
        const float dx = cb[n] - mx;
        const float dy = cb[N + n] - my;
        const float dz = cb[2 * N + n] - mz;
        r = fmaxf(r, sqrtf(dx * dx + dy * dy + dz * dz));
    }
    for (int off = 32; off > 0; off >>= 1) r = fmaxf(r, __shfl_down(r, off));
    __shared__ float red[4];
    const int lane = threadIdx.x & 63;
    const int wv   = threadIdx.x >> 6;
    if (lane == 0) red[wv] = r;
    __syncthreads();
    if (threadIdx.x == 0) {
        const int nw = blockDim.x >> 6;
        float t = 0.f;
        for (int w = 0; w < nw; ++w) t = fmaxf(t, red[w]);
        atomicMax(&ws_max[b], __float_as_uint(t));
    }
}

// norm coords + voxel idx + per-voxel counts; atomic's RETURN VALUE = rank
// within voxel (jloc) -> no separate rank pass needed later.
__global__ void k_points(const float* __restrict__ coords, const float* __restrict__ ws_sums,
                         const unsigned int* __restrict__ ws_max,
                         float* __restrict__ norm_out, int* __restrict__ idx_ws,
                         int* __restrict__ jloc, int* __restrict__ counts, int N) {
    const int b = blockIdx.y;
    const int n = blockIdx.x * blockDim.x + threadIdx.x;
    if (n >= N) return;
    const float invN  = 1.0f / (float)N;
    const float scale = 2.0f * __uint_as_float(ws_max[b]);
    const float* cb = coords + (size_t)b * 3 * N;
    float* nb = norm_out + (size_t)b * 3 * N;

    int flat = 0;
#pragma unroll
    for (int d = 0; d < 3; ++d) {
        const float mean = ws_sums[b * 3 + d] * invN;
        float nc = (cb[d * N + n] - mean) / scale + 0.5f;
        nc = fminf(fmaxf(nc * (float)RESV, 0.0f), (float)(RESV - 1));
        nb[d * N + n] = nc;
        flat = flat * RESV + (int)rintf(nc);
    }
    idx_ws[(size_t)b * N + n] = flat;
    jloc[(size_t)b * N + n] = atomicAdd(&counts[b * R3V + flat], 1);
}

// Per-batch exclusive scan of counts -> start (stride R3P1, sentinel start[R3V]=N)
__global__ __launch_bounds__(1024, 1) void k_scan(const int* __restrict__ counts,
                                                  int* __restrict__ start, int N) {
    const int b = blockIdx.x;
    const int t = threadIdx.x;
    const int base  = b * R3V + t * 32;
    const int baseS = b * R3P1 + t * 32;
    int c[32];
    int T = 0;
#pragma unroll
    for (int i = 0; i < 32; ++i) { c[i] = counts[base + i]; T += c[i]; }
    int incl = T;
    const int lane = t & 63;
    for (int off = 1; off < 64; off <<= 1) {
        int y = __shfl_up(incl, off);
        if (lane >= off) incl += y;
    }
    __shared__ int wsum[16];
    __shared__ int wbase[16];
    const int w = t >> 6;
    if (lane == 63) wsum[w] = incl;
    __syncthreads();
    if (t == 0) {
        int run = 0;
        for (int i = 0; i < 16; ++i) { wbase[i] = run; run += wsum[i]; }
    }
    __syncthreads();
    int run = wbase[w] + incl - T;  // exclusive prefix
#pragma unroll
    for (int i = 0; i < 32; ++i) {
        start[baseS + i] = run;
        run += c[i];
    }
    if (t == 1023) start[b * R3P1 + R3V] = run;  // == N
}

// feats [B,64,N] -> fTs [B,N,64] bf16, rows in SORTED (voxel) order.
// Row index j = start[v] + jloc[n]  (no atomics). Also voxid[j] = v.
__global__ __launch_bounds__(1024, 2) void k_transpose_perm(
        const float* __restrict__ feats, const int* __restrict__ idx_ws,
        const int* __restrict__ jloc, const int* __restrict__ startv,
        __hip_bfloat16* __restrict__ fTs, int* __restrict__ voxid, int N) {
    __shared__ float tile[64][257];
    __shared__ int jrow[256];
    const int b  = blockIdx.y;
    const int n0 = blockIdx.x * 256;
    const int t  = threadIdx.x;
    const int nn = t & 255;
    const int c0 = t >> 8;  // 0..3
    const float* fb = feats + (size_t)b * 64 * N;
#pragma unroll
    for (int k = 0; k < 16; ++k) {
        const int cc = c0 + k * 4;
        const int n  = n0 + nn;
        tile[cc][nn] = (n < N) ? fb[(size_t)cc * N + n] : 0.f;
    }
    if (t < 256) {
        const int n = n0 + t;
        if (n < N) {
            const int v = idx_ws[(size_t)b * N + n];
            const int j = startv[(size_t)b * R3P1 + v] + jloc[(size_t)b * N + n];
            jrow[t] = j;
            voxid[(size_t)b * N + j] = v;
        }
    }
    __syncthreads();
    const int wv   = t >> 6;  // 0..15
    const int lane = t & 63;  // channel
    __hip_bfloat16* fo = fTs + (size_t)b * N * 64;
#pragma unroll
    for (int pass = 0; pass < 16; ++pass) {
        const int p = wv + pass * 16;  // 0..255
        if (n0 + p < N) {
            const int row = jrow[p];
            fo[(size_t)row * 64 + lane] = __float2bfloat16(tile[lane][p]);
        }
    }
}

__device__ __forceinline__ float blo(unsigned int u) { return __uint_as_float(u << 16); }
__device__ __forceinline__ float bhi(unsigned int u) { return __uint_as_float(u & 0xffff0000u); }

// Atomic-free segmented reduction over sorted rows.
// Ownership: the chunk containing a segment's START processes the WHOLE
// segment (reading past chunk end if needed) -> exactly one plain store per
// occupied voxel; gridT needs no zero-init (k_fin masks cnt==0).
// Lane mapping: half = row parity, lc = channel pair; each dword load fetches
// 2 bf16 channels; a wave instruction covers 2 rows x 128B. Halves combined
// with one shfl_xor(32) pair per segment.
__global__ __launch_bounds__(256) void k_gather4(const __hip_bfloat16* __restrict__ fTs,
                                                 const int* __restrict__ voxid,
                                                 const int* __restrict__ startv,
                                                 float* __restrict__ gridT, int N, int nchunk) {
    const int w     = threadIdx.x >> 6;
    const int lane  = threadIdx.x & 63;
    const int half  = lane >> 5;   // row parity
    const int lc    = lane & 31;   // channel pair: channels 2lc, 2lc+1
    const int chunk = blockIdx.x * 4 + w;
    if (chunk >= nchunk) return;
    const int b    = blockIdx.y;
    const int c0   = chunk * CH;
    const int end0 = min(c0 + CH, N);
    const unsigned int* fb = (const unsigned int*)(fTs + (size_t)b * N * 64);  // row*32+lc
    const int* vi = voxid  + (size_t)b * N;
    const int* sv = startv + (size_t)b * R3P1;
    float* gT = gridT + (size_t)b * R3V * 64;

    // first segment starting inside [c0, end0)
    int j;
    {
        const int v = vi[c0];
        const int s = sv[v];
        j = (s < c0) ? sv[v + 1] : s;  // partial head segment owned by earlier chunk
    }
    while (j < end0) {
        const int v = vi[j];           // wave-uniform
        const int e = sv[v + 1];
        float ax = 0.f, ay = 0.f;
        int r = j + half;
        for (; r + 2 < e; r += 4) {    // 2 independent loads in flight per lane
            const unsigned int u0 = fb[(size_t)r * 32 + lc];
            const unsigned int u1 = fb[(size_t)(r + 2) * 32 + lc];
            ax += blo(u0) + blo(u1);
            ay += bhi(u0) + bhi(u1);
        }
        for (; r < e; r += 2) {
            const unsigned int u = fb[(size_t)r * 32 + lc];
            ax += blo(u);
            ay += bhi(u);
        }
        ax += __shfl_xor(ax, 32);
        ay += __shfl_xor(ay, 32);
        if (half == 0) {
            *(float2*)(gT + (size_t)v * 64 + 2 * lc) = make_float2(ax, ay);
        }
        j = e;
    }
}

// gridT [B,R3,64] -> grid [B,64,R3], fused with /cnt; cnt==0 -> exact 0
// (gridT never zero-initialized; unoccupied voxels hold garbage we never use).
__global__ __launch_bounds__(256) void k_fin(const float* __restrict__ gridT,
                                             const int* __restrict__ counts,
                                             float* __restrict__ grid) {
    __shared__ float tile[64][65];
    const int b    = blockIdx.y;
    const int v0   = blockIdx.x * 64;
    const int t    = threadIdx.x;
    const int lane = t & 63;
    const int w    = t >> 6;  // 0..3
    const float* gT = gridT + ((size_t)b * R3V + v0) * 64;
#pragma unroll
    for (int k = 0; k < 16; ++k) {
        const int r = w + k * 4;
        tile[r][lane] = gT[(size_t)r * 64 + lane];
    }
    __syncthreads();
    const int cnt  = counts[(size_t)b * R3V + v0 + lane];
    const float rc = 1.0f / fmaxf((float)cnt, 1.0f);
    const bool occ = cnt > 0;
    float* gb = grid + (size_t)b * 64 * R3V;
#pragma unroll
    for (int k = 0; k < 16; ++k) {
        const int c = w + k * 4;
        gb[(size_t)c * R3V + v0 + lane] = occ ? tile[lane][c] * rc : 0.0f;
    }
}

// ============================ fallback: R2 LDS-atomic scatter ============================

__device__ __forceinline__ int swz(int v) {
    return v ^ ((v >> 5) & 31) ^ ((v >> 10) & 31);
}

__global__ void k_recip_fb(const int* __restrict__ cnt, float* __restrict__ recip, int total) {
    const int i = blockIdx.x * blockDim.x + threadIdx.x;
    if (i < total) recip[i] = 1.0f / fmaxf((float)cnt[i], 1.0f);
}

__global__ __launch_bounds__(1024, 1) void k_scatter_lds(
        const float* __restrict__ feats, const int* __restrict__ idx_ws,
        const float* __restrict__ recip, float* __restrict__ grid, int N, int C) {
    extern __shared__ float acc[];
    const int bc  = blockIdx.x;
    const int b   = bc / C;
    const int tid = threadIdx.x;
    for (int i = tid * 4; i < R3V; i += blockDim.x * 4)
        *(float4*)(acc + i) = make_float4(0.f, 0.f, 0.f, 0.f);
    __syncthreads();
    const float* fb = feats  + (size_t)bc * N;
    const int*   ib = idx_ws + (size_t)b  * N;
    const int n4 = (N / 4) * 4;
    for (int n = tid * 4; n < n4; n += blockDim.x * 4) {
        const float4 f = *(const float4*)(fb + n);
        const int4  ix = *(const int4*)(ib + n);
        atomicAdd(&acc[swz(ix.x)], f.x);
        atomicAdd(&acc[swz(ix.y)], f.y);
        atomicAdd(&acc[swz(ix.z)], f.z);
        atomicAdd(&acc[swz(ix.w)], f.w);
    }
    for (int n = n4 + tid; n < N; n += blockDim.x) atomicAdd(&acc[swz(ib[n])], fb[n]);
    __syncthreads();
    const float* rb = recip + (size_t)b * R3V;
    float*       gb = grid  + (size_t)bc * R3V;
    for (int i = tid; i < R3V; i += blockDim.x)
        gb[i] = acc[swz(i)] * rb[i];
}

// ============================ launch ============================

extern "C" void kernel_launch(void* const* d_in, const int* in_sizes, int n_in,
                              void* d_out, int out_size, void* d_ws, size_t ws_size,
                              hipStream_t stream) {
    const float* feats  = (const float*)d_in[0];
    const float* coords = (const float*)d_in[1];

    const long long s0 = in_sizes[0], s1 = in_sizes[1];
    const int BC = (int)(((long long)out_size - s1) / R3V);  // B*C
    const int N  = (int)(s0 / BC);
    const int B  = (int)(s1 / (3LL * N));
    const int C  = BC / B;

    float* out_grid = (float*)d_out;               // [B, C, R3]
    float* out_norm = out_grid + (size_t)BC * R3V; // [B, 3, N]

    // ws layout (float32 slots)
    const size_t BR3 = (size_t)B * R3V;
    const size_t BN  = (size_t)B * N;
    const size_t o_counts = 64;
    const size_t o_start  = o_counts + BR3;
    const size_t o_recip  = o_start + (size_t)B * R3P1;  // fallback only
    const size_t o_idx    = o_recip + BR3;
    const size_t o_jloc   = o_idx + BN;
    const size_t o_voxid  = o_jloc + BN;
    size_t o_gridT = (o_voxid + BN + 63) & ~(size_t)63;
    size_t o_fTs   = (o_gridT + BR3 * 64 + 63) & ~(size_t)63;
    const size_t need = (o_fTs + (BN * 64 + 1) / 2) * sizeof(float);  // fTs is bf16

    float*        ws_sums = (float*)d_ws;
    unsigned int* ws_max  = (unsigned int*)((float*)d_ws + 32);
    int*          counts  = (int*)d_ws + o_counts;
    int*          startv  = (int*)d_ws + o_start;
    float*        recip   = (float*)d_ws + o_recip;
    int*          idx_ws  = (int*)d_ws + o_idx;
    int*          jloc    = (int*)d_ws + o_jloc;
    int*          voxid   = (int*)d_ws + o_voxid;
    float*        gridT   = (float*)d_ws + o_gridT;
    __hip_bfloat16* fTs   = (__hip_bfloat16*)((float*)d_ws + o_fTs);

    // zero header + counts (contiguous). gridT intentionally NOT zeroed.
    hipMemsetAsync(d_ws, 0, (64 + BR3) * sizeof(float), stream);

    const int BLK = 256;
    dim3 gRed(32, B);
    k_sums<<<gRed, BLK, 0, stream>>>(coords, ws_sums, N);
    k_maxrad<<<gRed, BLK, 0, stream>>>(coords, ws_sums, ws_max, N);

    dim3 gPts((N + BLK - 1) / BLK, B);
    k_points<<<gPts, BLK, 0, stream>>>(coords, ws_sums, ws_max, out_norm, idx_ws, jloc, counts, N);

    if (ws_size >= need && C == 64) {
        k_scan<<<dim3(B), 1024, 0, stream>>>(counts, startv, N);
        dim3 gT((N + 255) / 256, B);
        k_transpose_perm<<<gT, 1024, 0, stream>>>(feats, idx_ws, jloc, startv, fTs, voxid, N);
        const int nchunk = (N + CH - 1) / CH;
        dim3 gG((nchunk + 3) / 4, B);
        k_gather4<<<gG, 256, 0, stream>>>(fTs, voxid, startv, gridT, N, nchunk);
        dim3 gF(R3V / 64, B);
        k_fin<<<gF, 256, 0, stream>>>(gridT, counts, out_grid);
    } else {
        const int tot = B * R3V;
        k_recip_fb<<<(tot + BLK - 1) / BLK, BLK, 0, stream>>>(counts, recip, tot);
        k_scatter_lds<<<dim3(BC), 1024, R3V * sizeof(float), stream>>>(
            feats, idx_ws, recip, out_grid, N, C);
    }
}

// Round 7
// 239.739 us; speedup vs baseline: 2.5140x; 1.1287x over previous
//
#include <hip/hip_runtime.h>
#include <hip/hip_bf16.h>

#define RESV 32
#define R3V (RESV * RESV * RESV)
#define R3P1 (R3V + 1)
#define CH 64  // sorted points per wave-chunk in k_gather4

__device__ __forceinline__ unsigned short f2bf(float f) {
    __hip_bfloat16 h = __float2bfloat16(f);  // RNE, matches prior rounds
    unsigned short u;
    __builtin_memcpy(&u, &h, 2);
    return u;
}

// ============================ small prep kernels ============================

__global__ void k_zero(float4* __restrict__ p, int n4) {
    const int i = blockIdx.x * blockDim.x + threadIdx.x;
    if (i < n4) p[i] = make_float4(0.f, 0.f, 0.f, 0.f);
}

__global__ void k_sums(const float* __restrict__ coords, float* __restrict__ ws_sums, int N) {
    const int b = blockIdx.y;
    const float* cb = coords + (size_t)b * 3 * N;
    float sx = 0.f, sy = 0.f, sz = 0.f;
    for (int n = blockIdx.x * blockDim.x + threadIdx.x; n < N; n += gridDim.x * blockDim.x) {
        sx += cb[n];
        sy += cb[N + n];
        sz += cb[2 * N + n];
    }
    for (int off = 32; off > 0; off >>= 1) {
        sx += __shfl_down(sx, off);
        sy += __shfl_down(sy, off);
        sz += __shfl_down(sz, off);
    }
    __shared__ float red[3][4];
    const int lane = threadIdx.x & 63;
    const int wv   = threadIdx.x >> 6;
    if (lane == 0) { red[0][wv] = sx; red[1][wv] = sy; red[2][wv] = sz; }
    __syncthreads();
    if (threadIdx.x == 0) {
        float tx = 0.f, ty = 0.f, tz = 0.f;
        const int nw = blockDim.x >> 6;
        for (int w = 0; w < nw; ++w) { tx += red[0][w]; ty += red[1][w]; tz += red[2][w]; }
        atomicAdd(&ws_sums[b * 3 + 0], tx);
        atomicAdd(&ws_sums[b * 3 + 1], ty);
        atomicAdd(&ws_sums[b * 3 + 2], tz);
    }
}

__global__ void k_maxrad(const float* __restrict__ coords, const float* __restrict__ ws_sums,
                         unsigned int* __restrict__ ws_max, int N) {
    const int b = blockIdx.y;
    const float invN = 1.0f / (float)N;
    const float mx = ws_sums[b * 3 + 0] * invN;
    const float my = ws_sums[b * 3 + 1] * invN;
    const float mz = ws_sums[b * 3 + 2] * invN;
    const float* cb = coords + (size_t)b * 3 * N;
    float r = 0.f;
    for (int n = blockIdx.x * blockDim.x + threadIdx.x; n < N; n += gridDim.x * blockDim.x) {
        const float dx = cb[n] - mx;
        const float dy = cb[N + n] - my;
        const float dz = cb[2 * N + n] - mz;
        r = fmaxf(r, sqrtf(dx * dx + dy * dy + dz * dz));
    }
    for (int off = 32; off > 0; off >>= 1) r = fmaxf(r, __shfl_down(r, off));
    __shared__ float red[4];
    const int lane = threadIdx.x & 63;
    const int wv   = threadIdx.x >> 6;
    if (lane == 0) red[wv] = r;
    __syncthreads();
    if (threadIdx.x == 0) {
        const int nw = blockDim.x >> 6;
        float t = 0.f;
        for (int w = 0; w < nw; ++w) t = fmaxf(t, red[w]);
        atomicMax(&ws_max[b], __float_as_uint(t));
    }
}

// norm coords + voxel idx + per-voxel counts; atomic's return value = rank (jloc)
__global__ void k_points(const float* __restrict__ coords, const float* __restrict__ ws_sums,
                         const unsigned int* __restrict__ ws_max,
                         float* __restrict__ norm_out, int* __restrict__ idx_ws,
                         int* __restrict__ jloc, int* __restrict__ counts, int N) {
    const int b = blockIdx.y;
    const int n = blockIdx.x * blockDim.x + threadIdx.x;
    if (n >= N) return;
    const float invN  = 1.0f / (float)N;
    const float scale = 2.0f * __uint_as_float(ws_max[b]);
    const float* cb = coords + (size_t)b * 3 * N;
    float* nb = norm_out + (size_t)b * 3 * N;

    int flat = 0;
#pragma unroll
    for (int d = 0; d < 3; ++d) {
        const float mean = ws_sums[b * 3 + d] * invN;
        float nc = (cb[d * N + n] - mean) / scale + 0.5f;
        nc = fminf(fmaxf(nc * (float)RESV, 0.0f), (float)(RESV - 1));
        nb[d * N + n] = nc;
        flat = flat * RESV + (int)rintf(nc);
    }
    idx_ws[(size_t)b * N + n] = flat;
    jloc[(size_t)b * N + n] = atomicAdd(&counts[b * R3V + flat], 1);
}

// Per-batch exclusive scan of counts -> start (stride R3P1, sentinel start[R3V]=N)
__global__ __launch_bounds__(1024, 1) void k_scan(const int* __restrict__ counts,
                                                  int* __restrict__ start, int N) {
    const int b = blockIdx.x;
    const int t = threadIdx.x;
    const int base  = b * R3V + t * 32;
    const int baseS = b * R3P1 + t * 32;
    int c[32];
    int T = 0;
#pragma unroll
    for (int i = 0; i < 32; ++i) { c[i] = counts[base + i]; T += c[i]; }
    int incl = T;
    const int lane = t & 63;
    for (int off = 1; off < 64; off <<= 1) {
        int y = __shfl_up(incl, off);
        if (lane >= off) incl += y;
    }
    __shared__ int wsum[16];
    __shared__ int wbase[16];
    const int w = t >> 6;
    if (lane == 63) wsum[w] = incl;
    __syncthreads();
    if (t == 0) {
        int run = 0;
        for (int i = 0; i < 16; ++i) { wbase[i] = run; run += wsum[i]; }
    }
    __syncthreads();
    int run = wbase[w] + incl - T;  // exclusive prefix
#pragma unroll
    for (int i = 0; i < 32; ++i) {
        start[baseS + i] = run;
        run += c[i];
    }
    if (t == 1023) start[b * R3P1 + R3V] = run;  // == N
}

// feats [B,64,N] fp32 -> fTs [B,N,64] bf16, rows in SORTED (voxel) order.
// bf16 conversion on load; LDS tile is ushort [point][channel] (34 KB).
// Store phase: dword per lane (2 channels), 32 lanes = one 128B row,
// 2 rows per wave instruction, 8 passes.
__global__ __launch_bounds__(1024, 2) void k_transpose_perm(
        const float* __restrict__ feats, const int* __restrict__ idx_ws,
        const int* __restrict__ jloc, const int* __restrict__ startv,
        unsigned int* __restrict__ fTs32, int* __restrict__ voxid, int N) {
    __shared__ unsigned short tile[256][66];  // pad 66: bank=(p*33+lc)&31, conflict-free
    __shared__ int jrow[256];
    const int b  = blockIdx.y;
    const int n0 = blockIdx.x * 256;
    const int t  = threadIdx.x;
    const float* fb = feats + (size_t)b * 64 * N;

    // ---- load + convert: c = t>>4 (0..63), q = t&15; 4 float4 loads along n ----
    const int c = t >> 4;
    const int q = t & 15;
    if (n0 + 256 <= N) {
#pragma unroll
        for (int i = 0; i < 4; ++i) {
            const int nn = q * 4 + i * 64;
            const float4 f = *(const float4*)(fb + (size_t)c * N + n0 + nn);
            tile[nn + 0][c] = f2bf(f.x);
            tile[nn + 1][c] = f2bf(f.y);
            tile[nn + 2][c] = f2bf(f.z);
            tile[nn + 3][c] = f2bf(f.w);
        }
    } else {
        for (int i = 0; i < 4; ++i) {
            const int nn = q * 4 + i * 64;
            for (int u = 0; u < 4; ++u) {
                const int n = n0 + nn + u;
                tile[nn + u][c] = f2bf((n < N) ? fb[(size_t)c * N + n] : 0.f);
            }
        }
    }
    if (t < 256) {
        const int n = n0 + t;
        if (n < N) {
            const int v = idx_ws[(size_t)b * N + n];
            const int j = startv[(size_t)b * R3P1 + v] + jloc[(size_t)b * N + n];
            jrow[t] = j;
            voxid[(size_t)b * N + j] = v;
        }
    }
    __syncthreads();

    // ---- permuted store: 8 passes, 2 rows per wave instruction ----
    const int wv   = t >> 6;        // 0..15
    const int lane = t & 63;
    const int lc   = lane & 31;     // channel pair
    const int ph   = lane >> 5;     // row parity within pass
    unsigned int* fo = fTs32 + (size_t)b * N * 32;
#pragma unroll
    for (int k = 0; k < 8; ++k) {
        const int p = k * 32 + wv * 2 + ph;  // 0..255
        if (n0 + p < N) {
            const unsigned int d = *(const unsigned int*)&tile[p][2 * lc];
            fo[(size_t)jrow[p] * 32 + lc] = d;
        }
    }
}

__device__ __forceinline__ float blo(unsigned int u) { return __uint_as_float(u << 16); }
__device__ __forceinline__ float bhi(unsigned int u) { return __uint_as_float(u & 0xffff0000u); }

// Atomic-free segmented reduction over sorted rows (chunk owns segments that
// START inside it; reads may run past chunk end). One plain store per
// occupied voxel; gridT needs no zero-init (k_fin masks cnt==0).
__global__ __launch_bounds__(256) void k_gather4(const __hip_bfloat16* __restrict__ fTs,
                                                 const int* __restrict__ voxid,
                                                 const int* __restrict__ startv,
                                                 float* __restrict__ gridT, int N, int nchunk) {
    const int w     = threadIdx.x >> 6;
    const int lane  = threadIdx.x & 63;
    const int half  = lane >> 5;   // row parity
    const int lc    = lane & 31;   // channel pair
    const int chunk = blockIdx.x * 4 + w;
    if (chunk >= nchunk) return;
    const int b    = blockIdx.y;
    const int c0   = chunk * CH;
    const int end0 = min(c0 + CH, N);
    const unsigned int* fb = (const unsigned int*)(fTs + (size_t)b * N * 64);
    const int* vi = voxid  + (size_t)b * N;
    const int* sv = startv + (size_t)b * R3P1;
    float* gT = gridT + (size_t)b * R3V * 64;

    int j;
    {
        const int v = vi[c0];
        const int s = sv[v];
        j = (s < c0) ? sv[v + 1] : s;  // partial head segment owned by earlier chunk
    }
    while (j < end0) {
        const int v = vi[j];           // wave-uniform
        const int e = sv[v + 1];
        float ax = 0.f, ay = 0.f;
        int r = j + half;
        for (; r + 6 < e; r += 8) {    // 4 loads in flight per lane
            const unsigned int u0 = fb[(size_t)(r + 0) * 32 + lc];
            const unsigned int u1 = fb[(size_t)(r + 2) * 32 + lc];
            const unsigned int u2 = fb[(size_t)(r + 4) * 32 + lc];
            const unsigned int u3 = fb[(size_t)(r + 6) * 32 + lc];
            ax += (blo(u0) + blo(u1)) + (blo(u2) + blo(u3));
            ay += (bhi(u0) + bhi(u1)) + (bhi(u2) + bhi(u3));
        }
        for (; r < e; r += 2) {
            const unsigned int u = fb[(size_t)r * 32 + lc];
            ax += blo(u);
            ay += bhi(u);
        }
        ax += __shfl_xor(ax, 32);
        ay += __shfl_xor(ay, 32);
        if (half == 0) {
            *(float2*)(gT + (size_t)v * 64 + 2 * lc) = make_float2(ax, ay);
        }
        j = e;
    }
}

// gridT [B,R3,64] -> grid [B,64,R3], fused with /cnt; cnt==0 -> exact 0
__global__ __launch_bounds__(256) void k_fin(const float* __restrict__ gridT,
                                             const int* __restrict__ counts,
                                             float* __restrict__ grid) {
    __shared__ float tile[64][65];
    const int b    = blockIdx.y;
    const int v0   = blockIdx.x * 64;
    const int t    = threadIdx.x;
    const int lane = t & 63;
    const int w    = t >> 6;  // 0..3
    const float* gT = gridT + ((size_t)b * R3V + v0) * 64;
#pragma unroll
    for (int k = 0; k < 16; ++k) {
        const int r = w + k * 4;
        tile[r][lane] = gT[(size_t)r * 64 + lane];
    }
    __syncthreads();
    const int cnt  = counts[(size_t)b * R3V + v0 + lane];
    const float rc = 1.0f / fmaxf((float)cnt, 1.0f);
    const bool occ = cnt > 0;
    float* gb = grid + (size_t)b * 64 * R3V;
#pragma unroll
    for (int k = 0; k < 16; ++k) {
        const int c = w + k * 4;
        gb[(size_t)c * R3V + v0 + lane] = occ ? tile[lane][c] * rc : 0.0f;
    }
}

// ============================ fallback: R2 LDS-atomic scatter ============================

__device__ __forceinline__ int swz(int v) {
    return v ^ ((v >> 5) & 31) ^ ((v >> 10) & 31);
}

__global__ void k_recip_fb(const int* __restrict__ cnt, float* __restrict__ recip, int total) {
    const int i = blockIdx.x * blockDim.x + threadIdx.x;
    if (i < total) recip[i] = 1.0f / fmaxf((float)cnt[i], 1.0f);
}

__global__ __launch_bounds__(1024, 1) void k_scatter_lds(
        const float* __restrict__ feats, const int* __restrict__ idx_ws,
        const float* __restrict__ recip, float* __restrict__ grid, int N, int C) {
    extern __shared__ float acc[];
    const int bc  = blockIdx.x;
    const int b   = bc / C;
    const int tid = threadIdx.x;
    for (int i = tid * 4; i < R3V; i += blockDim.x * 4)
        *(float4*)(acc + i) = make_float4(0.f, 0.f, 0.f, 0.f);
    __syncthreads();
    const float* fb = feats  + (size_t)bc * N;
    const int*   ib = idx_ws + (size_t)b  * N;
    const int n4 = (N / 4) * 4;
    for (int n = tid * 4; n < n4; n += blockDim.x * 4) {
        const float4 f = *(const float4*)(fb + n);
        const int4  ix = *(const int4*)(ib + n);
        atomicAdd(&acc[swz(ix.x)], f.x);
        atomicAdd(&acc[swz(ix.y)], f.y);
        atomicAdd(&acc[swz(ix.z)], f.z);
        atomicAdd(&acc[swz(ix.w)], f.w);
    }
    for (int n = n4 + tid; n < N; n += blockDim.x) atomicAdd(&acc[swz(ib[n])], fb[n]);
    __syncthreads();
    const float* rb = recip + (size_t)b * R3V;
    float*       gb = grid  + (size_t)bc * R3V;
    for (int i = tid; i < R3V; i += blockDim.x)
        gb[i] = acc[swz(i)] * rb[i];
}

// ============================ launch ============================

extern "C" void kernel_launch(void* const* d_in, const int* in_sizes, int n_in,
                              void* d_out, int out_size, void* d_ws, size_t ws_size,
                              hipStream_t stream) {
    const float* feats  = (const float*)d_in[0];
    const float* coords = (const float*)d_in[1];

    const long long s0 = in_sizes[0], s1 = in_sizes[1];
    const int BC = (int)(((long long)out_size - s1) / R3V);  // B*C
    const int N  = (int)(s0 / BC);
    const int B  = (int)(s1 / (3LL * N));
    const int C  = BC / B;

    float* out_grid = (float*)d_out;               // [B, C, R3]
    float* out_norm = out_grid + (size_t)BC * R3V; // [B, 3, N]

    // ws layout (float32 slots)
    const size_t BR3 = (size_t)B * R3V;
    const size_t BN  = (size_t)B * N;
    const size_t o_counts = 64;
    const size_t o_start  = o_counts + BR3;
    const size_t o_recip  = o_start + (size_t)B * R3P1;  // fallback only
    const size_t o_idx    = o_recip + BR3;
    const size_t o_jloc   = o_idx + BN;
    const size_t o_voxid  = o_jloc + BN;
    size_t o_gridT = (o_voxid + BN + 63) & ~(size_t)63;
    size_t o_fTs   = (o_gridT + BR3 * 64 + 63) & ~(size_t)63;
    const size_t need = (o_fTs + (BN * 64 + 1) / 2) * sizeof(float);  // fTs is bf16

    float*        ws_sums = (float*)d_ws;
    unsigned int* ws_max  = (unsigned int*)((float*)d_ws + 32);
    int*          counts  = (int*)d_ws + o_counts;
    int*          startv  = (int*)d_ws + o_start;
    float*        recip   = (float*)d_ws + o_recip;
    int*          idx_ws  = (int*)d_ws + o_idx;
    int*          jloc    = (int*)d_ws + o_jloc;
    int*          voxid   = (int*)d_ws + o_voxid;
    float*        gridT   = (float*)d_ws + o_gridT;
    __hip_bfloat16* fTs   = (__hip_bfloat16*)((float*)d_ws + o_fTs);

    // zero header + counts via our own kernel (keeps rocclr fills out of the graph)
    const int zero4 = (int)((64 + BR3) / 4);
    k_zero<<<(zero4 + 255) / 256, 256, 0, stream>>>((float4*)d_ws, zero4);

    const int BLK = 256;
    dim3 gRed(32, B);
    k_sums<<<gRed, BLK, 0, stream>>>(coords, ws_sums, N);
    k_maxrad<<<gRed, BLK, 0, stream>>>(coords, ws_sums, ws_max, N);

    dim3 gPts((N + BLK - 1) / BLK, B);
    k_points<<<gPts, BLK, 0, stream>>>(coords, ws_sums, ws_max, out_norm, idx_ws, jloc, counts, N);

    if (ws_size >= need && C == 64) {
        k_scan<<<dim3(B), 1024, 0, stream>>>(counts, startv, N);
        dim3 gT((N + 255) / 256, B);
        k_transpose_perm<<<gT, 1024, 0, stream>>>(feats, idx_ws, jloc, startv,
                                                  (unsigned int*)fTs, voxid, N);
        const int nchunk = (N + CH - 1) / CH;
        dim3 gG((nchunk + 3) / 4, B);
        k_gather4<<<gG, 256, 0, stream>>>(fTs, voxid, startv, gridT, N, nchunk);
        dim3 gF(R3V / 64, B);
        k_fin<<<gF, 256, 0, stream>>>(gridT, counts, out_grid);
    } else {
        const int tot = B * R3V;
        k_recip_fb<<<(tot + BLK - 1) / BLK, BLK, 0, stream>>>(counts, recip, tot);
        k_scatter_lds<<<dim3(BC), 1024, R3V * sizeof(float), stream>>>(
            feats, idx_ws, recip, out_grid, N, C);
    }
}

// Round 9
// 231.004 us; speedup vs baseline: 2.6090x; 1.0378x over previous
//
#include <hip/hip_runtime.h>
#include <hip/hip_bf16.h>

#define RESV 32
#define R3V (RESV * RESV * RESV)
#define R3P1 (R3V + 1)
#define CH 64  // sorted points per wave-chunk in k_gather4

__device__ __forceinline__ unsigned short f2bf(float f) {
    __hip_bfloat16 h = __float2bfloat16(f);  // RNE
    unsigned short u;
    __builtin_memcpy(&u, &h, 2);
    return u;
}
__device__ __forceinline__ unsigned int pkbf(float lo, float hi) {
    return (unsigned int)f2bf(lo) | ((unsigned int)f2bf(hi) << 16);
}
__device__ __forceinline__ float blo(unsigned int u) { return __uint_as_float(u << 16); }
__device__ __forceinline__ float bhi(unsigned int u) { return __uint_as_float(u & 0xffff0000u); }

// ============================ small prep kernels ============================

__global__ void k_zero(float4* __restrict__ p, int n4) {
    const int i = blockIdx.x * blockDim.x + threadIdx.x;
    if (i < n4) p[i] = make_float4(0.f, 0.f, 0.f, 0.f);
}

__global__ void k_sums(const float* __restrict__ coords, float* __restrict__ ws_sums, int N) {
    const int b = blockIdx.y;
    const float* cb = coords + (size_t)b * 3 * N;
    float sx = 0.f, sy = 0.f, sz = 0.f;
    for (int n = blockIdx.x * blockDim.x + threadIdx.x; n < N; n += gridDim.x * blockDim.x) {
        sx += cb[n];
        sy += cb[N + n];
        sz += cb[2 * N + n];
    }
    for (int off = 32; off > 0; off >>= 1) {
        sx += __shfl_down(sx, off);
        sy += __shfl_down(sy, off);
        sz += __shfl_down(sz, off);
    }
    __shared__ float red[3][4];
    const int lane = threadIdx.x & 63;
    const int wv   = threadIdx.x >> 6;
    if (lane == 0) { red[0][wv] = sx; red[1][wv] = sy; red[2][wv] = sz; }
    __syncthreads();
    if (threadIdx.x == 0) {
        float tx = 0.f, ty = 0.f, tz = 0.f;
        const int nw = blockDim.x >> 6;
        for (int w = 0; w < nw; ++w) { tx += red[0][w]; ty += red[1][w]; tz += red[2][w]; }
        atomicAdd(&ws_sums[b * 3 + 0], tx);
        atomicAdd(&ws_sums[b * 3 + 1], ty);
        atomicAdd(&ws_sums[b * 3 + 2], tz);
    }
}

__global__ void k_maxrad(const float* __restrict__ coords, const float* __restrict__ ws_sums,
                         unsigned int* __restrict__ ws_max, int N) {
    const int b = blockIdx.y;
    const float invN = 1.0f / (float)N;
    const float mx = ws_sums[b * 3 + 0] * invN;
    const float my = ws_sums[b * 3 + 1] * invN;
    const float mz = ws_sums[b * 3 + 2] * invN;
    const float* cb = coords + (size_t)b * 3 * N;
    float r = 0.f;
    for (int n = blockIdx.x * blockDim.x + threadIdx.x; n < N; n += gridDim.x * blockDim.x) {
        const float dx = cb[n] - mx;
        const float dy = cb[N + n] - my;
        const float dz = cb[2 * N + n] - mz;
        r = fmaxf(r, sqrtf(dx * dx + dy * dy + dz * dz));
    }
    for (int off = 32; off > 0; off >>= 1) r = fmaxf(r, __shfl_down(r, off));
    __shared__ float red[4];
    const int lane = threadIdx.x & 63;
    const int wv   = threadIdx.x >> 6;
    if (lane == 0) red[wv] = r;
    __syncthreads();
    if (threadIdx.x == 0) {
        const int nw = blockDim.x >> 6;
        float t = 0.f;
        for (int w = 0; w < nw; ++w) t = fmaxf(t, red[w]);
        atomicMax(&ws_max[b], __float_as_uint(t));
    }
}

// norm coords + voxel idx + per-voxel counts; atomic's return value = rank (jloc)
__global__ void k_points(const float* __restrict__ coords, const float* __restrict__ ws_sums,
                         const unsigned int* __restrict__ ws_max,
                         float* __restrict__ norm_out, int* __restrict__ idx_ws,
                         int* __restrict__ jloc, int* __restrict__ counts, int N) {
    const int b = blockIdx.y;
    const int n = blockIdx.x * blockDim.x + threadIdx.x;
    if (n >= N) return;
    const float invN  = 1.0f / (float)N;
    const float scale = 2.0f * __uint_as_float(ws_max[b]);
    const float* cb = coords + (size_t)b * 3 * N;
    float* nb = norm_out + (size_t)b * 3 * N;

    int flat = 0;
#pragma unroll
    for (int d = 0; d < 3; ++d) {
        const float mean = ws_sums[b * 3 + d] * invN;
        float nc = (cb[d * N + n] - mean) / scale + 0.5f;
        nc = fminf(fmaxf(nc * (float)RESV, 0.0f), (float)(RESV - 1));
        nb[d * N + n] = nc;
        flat = flat * RESV + (int)rintf(nc);
    }
    idx_ws[(size_t)b * N + n] = flat;
    jloc[(size_t)b * N + n] = atomicAdd(&counts[b * R3V + flat], 1);
}

// Per-batch exclusive scan of counts -> start (stride R3P1, sentinel start[R3V]=N)
__global__ __launch_bounds__(1024, 1) void k_scan(const int* __restrict__ counts,
                                                  int* __restrict__ start, int N) {
    const int b = blockIdx.x;
    const int t = threadIdx.x;
    const int base  = b * R3V + t * 32;
    const int baseS = b * R3P1 + t * 32;
    int c[32];
    int T = 0;
#pragma unroll
    for (int i = 0; i < 32; ++i) { c[i] = counts[base + i]; T += c[i]; }
    int incl = T;
    const int lane = t & 63;
    for (int off = 1; off < 64; off <<= 1) {
        int y = __shfl_up(incl, off);
        if (lane >= off) incl += y;
    }
    __shared__ int wsum[16];
    __shared__ int wbase[16];
    const int w = t >> 6;
    if (lane == 63) wsum[w] = incl;
    __syncthreads();
    if (t == 0) {
        int run = 0;
        for (int i = 0; i < 16; ++i) { wbase[i] = run; run += wsum[i]; }
    }
    __syncthreads();
    int run = wbase[w] + incl - T;  // exclusive prefix
#pragma unroll
    for (int i = 0; i < 32; ++i) {
        start[baseS + i] = run;
        run += c[i];
    }
    if (t == 1023) start[b * R3P1 + R3V] = run;  // == N
}

// feats [B,64,N] fp32 -> fTs [B,N,64] bf16, rows in SORTED (voxel) order.
__global__ __launch_bounds__(1024, 2) void k_transpose_perm(
        const float* __restrict__ feats, const int* __restrict__ idx_ws,
        const int* __restrict__ jloc, const int* __restrict__ startv,
        unsigned int* __restrict__ fTs32, int* __restrict__ voxid, int N) {
    __shared__ unsigned short tile[256][66];  // pad 66: near-conflict-free both phases
    __shared__ int jrow[256];
    const int b  = blockIdx.y;
    const int n0 = blockIdx.x * 256;
    const int t  = threadIdx.x;
    const float* fb = feats + (size_t)b * 64 * N;

    // ---- load + convert: c = t>>4 (0..63), q = t&15; 4 float4 loads along n ----
    const int c = t >> 4;
    const int q = t & 15;
    if (n0 + 256 <= N) {
#pragma unroll
        for (int i = 0; i < 4; ++i) {
            const int nn = q * 4 + i * 64;
            const float4 f = *(const float4*)(fb + (size_t)c * N + n0 + nn);
            tile[nn + 0][c] = f2bf(f.x);
            tile[nn + 1][c] = f2bf(f.y);
            tile[nn + 2][c] = f2bf(f.z);
            tile[nn + 3][c] = f2bf(f.w);
        }
    } else {
        for (int i = 0; i < 4; ++i) {
            const int nn = q * 4 + i * 64;
            for (int u = 0; u < 4; ++u) {
                const int n = n0 + nn + u;
                tile[nn + u][c] = f2bf((n < N) ? fb[(size_t)c * N + n] : 0.f);
            }
        }
    }
    if (t < 256) {
        const int n = n0 + t;
        if (n < N) {
            const int v = idx_ws[(size_t)b * N + n];
            const int j = startv[(size_t)b * R3P1 + v] + jloc[(size_t)b * N + n];
            jrow[t] = j;
            voxid[(size_t)b * N + j] = v;
        }
    }
    __syncthreads();

    // ---- permuted store: 8 passes, 2 rows per wave instruction ----
    const int wv   = t >> 6;        // 0..15
    const int lane = t & 63;
    const int lc   = lane & 31;     // channel pair
    const int ph   = lane >> 5;     // row parity within pass
    unsigned int* fo = fTs32 + (size_t)b * N * 32;
#pragma unroll
    for (int k = 0; k < 8; ++k) {
        const int p = k * 32 + wv * 2 + ph;  // 0..255
        if (n0 + p < N) {
            const unsigned int d = *(const unsigned int*)&tile[p][2 * lc];
            fo[(size_t)jrow[p] * 32 + lc] = d;
        }
    }
}

// Atomic-free segmented reduction over sorted rows (chunk owns segments that
// START inside it; reads may run past chunk end). One plain 128B store per
// occupied voxel; gridT (bf16) needs no zero-init (k_fin masks cnt==0).
// Lane map: p = lane>>4 (row parity 0..3), lc = lane&15 (channel quad).
// Each lane loads uint2 = 4 bf16 channels; 4-deep unroll = 16 rows in flight.
__global__ __launch_bounds__(256) void k_gather4(const unsigned int* __restrict__ fTs32,
                                                 const int* __restrict__ voxid,
                                                 const int* __restrict__ startv,
                                                 unsigned int* __restrict__ gridT2,
                                                 int N, int nchunk) {
    const int w     = threadIdx.x >> 6;
    const int lane  = threadIdx.x & 63;
    const int p     = lane >> 4;   // row parity 0..3
    const int lc    = lane & 15;   // channel quad: channels 4lc..4lc+3
    const int chunk = blockIdx.x * 4 + w;
    if (chunk >= nchunk) return;
    const int b    = blockIdx.y;
    const int c0   = chunk * CH;
    const int end0 = min(c0 + CH, N);
    const uint2* fb = (const uint2*)(fTs32 + (size_t)b * N * 32);  // row stride 16 uint2
    const int* vi = voxid  + (size_t)b * N;
    const int* sv = startv + (size_t)b * R3P1;
    uint2* gT = (uint2*)(gridT2) + (size_t)b * R3V * 16;

    int j;
    {
        const int v = vi[c0];
        const int s = sv[v];
        j = (s < c0) ? sv[v + 1] : s;  // partial head segment owned by earlier chunk
    }
    while (j < end0) {
        const int v = vi[j];           // wave-uniform
        const int e = sv[v + 1];
        float a0 = 0.f, a1 = 0.f, a2 = 0.f, a3 = 0.f;
        int r = j + p;
        for (; r + 12 < e; r += 16) {  // 4 uint2 loads in flight per lane
            const uint2 u0 = fb[(size_t)(r + 0) * 16 + lc];
            const uint2 u1 = fb[(size_t)(r + 4) * 16 + lc];
            const uint2 u2 = fb[(size_t)(r + 8) * 16 + lc];
            const uint2 u3 = fb[(size_t)(r + 12) * 16 + lc];
            a0 += (blo(u0.x) + blo(u1.x)) + (blo(u2.x) + blo(u3.x));
            a1 += (bhi(u0.x) + bhi(u1.x)) + (bhi(u2.x) + bhi(u3.x));
            a2 += (blo(u0.y) + blo(u1.y)) + (blo(u2.y) + blo(u3.y));
            a3 += (bhi(u0.y) + bhi(u1.y)) + (bhi(u2.y) + bhi(u3.y));
        }
        for (; r < e; r += 4) {
            const uint2 u = fb[(size_t)r * 16 + lc];
            a0 += blo(u.x);
            a1 += bhi(u.x);
            a2 += blo(u.y);
            a3 += bhi(u.y);
        }
        a0 += __shfl_xor(a0, 16); a0 += __shfl_xor(a0, 32);
        a1 += __shfl_xor(a1, 16); a1 += __shfl_xor(a1, 32);
        a2 += __shfl_xor(a2, 16); a2 += __shfl_xor(a2, 32);
        a3 += __shfl_xor(a3, 16); a3 += __shfl_xor(a3, 32);
        if (p == 0) {
            gT[(size_t)v * 16 + lc] = make_uint2(pkbf(a0, a1), pkbf(a2, a3));
        }
        j = e;
    }
}

// gridT bf16 [B,R3,64] -> grid fp32 [B,64,R3], fused with /cnt; cnt==0 -> 0
// FIX vs R7: LDS tile is filled VOXEL-major (tile[v][ch]) to match the
// reader (tile[lane=voxel][c=channel]); R7 filled it channel-major ->
// voxel<->channel transposed output divided by the wrong count.
__global__ __launch_bounds__(256) void k_fin(const unsigned int* __restrict__ gridT2,
                                             const int* __restrict__ counts,
                                             float* __restrict__ grid) {
    __shared__ float tile[64][65];
    const int b    = blockIdx.y;
    const int v0   = blockIdx.x * 64;
    const int t    = threadIdx.x;
    const int lane = t & 63;
    const int w    = t >> 6;  // 0..3
    const unsigned int* g = gridT2 + ((size_t)b * R3V + v0) * 32;
#pragma unroll
    for (int k = 0; k < 8; ++k) {
        const int i  = t + k * 256;  // 0..2047, == v*32 + cd
        const int v  = i >> 5;
        const int cd = i & 31;
        const unsigned int u = g[i];
        tile[v][2 * cd]     = blo(u);   // channel 2cd, voxel-major
        tile[v][2 * cd + 1] = bhi(u);   // channel 2cd+1
    }
    __syncthreads();
    const int cnt  = counts[(size_t)b * R3V + v0 + lane];
    const float rc = 1.0f / fmaxf((float)cnt, 1.0f);
    const bool occ = cnt > 0;
    float* gb = grid + (size_t)b * 64 * R3V;
#pragma unroll
    for (int k = 0; k < 16; ++k) {
        const int c = w + k * 4;
        gb[(size_t)c * R3V + v0 + lane] = occ ? tile[lane][c] * rc : 0.0f;
    }
}

// ============================ fallback: R2 LDS-atomic scatter ============================

__device__ __forceinline__ int swz(int v) {
    return v ^ ((v >> 5) & 31) ^ ((v >> 10) & 31);
}

__global__ void k_recip_fb(const int* __restrict__ cnt, float* __restrict__ recip, int total) {
    const int i = blockIdx.x * blockDim.x + threadIdx.x;
    if (i < total) recip[i] = 1.0f / fmaxf((float)cnt[i], 1.0f);
}

__global__ __launch_bounds__(1024, 1) void k_scatter_lds(
        const float* __restrict__ feats, const int* __restrict__ idx_ws,
        const float* __restrict__ recip, float* __restrict__ grid, int N, int C) {
    extern __shared__ float acc[];
    const int bc  = blockIdx.x;
    const int b   = bc / C;
    const int tid = threadIdx.x;
    for (int i = tid * 4; i < R3V; i += blockDim.x * 4)
        *(float4*)(acc + i) = make_float4(0.f, 0.f, 0.f, 0.f);
    __syncthreads();
    const float* fb = feats  + (size_t)bc * N;
    const int*   ib = idx_ws + (size_t)b  * N;
    const int n4 = (N / 4) * 4;
    for (int n = tid * 4; n < n4; n += blockDim.x * 4) {
        const float4 f = *(const float4*)(fb + n);
        const int4  ix = *(const int4*)(ib + n);
        atomicAdd(&acc[swz(ix.x)], f.x);
        atomicAdd(&acc[swz(ix.y)], f.y);
        atomicAdd(&acc[swz(ix.z)], f.z);
        atomicAdd(&acc[swz(ix.w)], f.w);
    }
    for (int n = n4 + tid; n < N; n += blockDim.x) atomicAdd(&acc[swz(ib[n])], fb[n]);
    __syncthreads();
    const float* rb = recip + (size_t)b * R3V;
    float*       gb = grid  + (size_t)bc * R3V;
    for (int i = tid; i < R3V; i += blockDim.x)
        gb[i] = acc[swz(i)] * rb[i];
}

// ============================ launch ============================

extern "C" void kernel_launch(void* const* d_in, const int* in_sizes, int n_in,
                              void* d_out, int out_size, void* d_ws, size_t ws_size,
                              hipStream_t stream) {
    const float* feats  = (const float*)d_in[0];
    const float* coords = (const float*)d_in[1];

    const long long s0 = in_sizes[0], s1 = in_sizes[1];
    const int BC = (int)(((long long)out_size - s1) / R3V);  // B*C
    const int N  = (int)(s0 / BC);
    const int B  = (int)(s1 / (3LL * N));
    const int C  = BC / B;

    float* out_grid = (float*)d_out;               // [B, C, R3]
    float* out_norm = out_grid + (size_t)BC * R3V; // [B, 3, N]

    // ws layout (float32 slots)
    const size_t BR3 = (size_t)B * R3V;
    const size_t BN  = (size_t)B * N;
    const size_t o_counts = 64;
    const size_t o_start  = o_counts + BR3;
    const size_t o_recip  = o_start + (size_t)B * R3P1;  // fallback only
    const size_t o_idx    = o_recip + BR3;
    const size_t o_jloc   = o_idx + BN;
    const size_t o_voxid  = o_jloc + BN;
    size_t o_gridT = (o_voxid + BN + 63) & ~(size_t)63;            // bf16: BR3*32 slots
    size_t o_fTs   = (o_gridT + BR3 * 32 + 63) & ~(size_t)63;      // bf16: BN*32 slots
    const size_t need = (o_fTs + BN * 32) * sizeof(float);

    float*        ws_sums = (float*)d_ws;
    unsigned int* ws_max  = (unsigned int*)((float*)d_ws + 32);
    int*          counts  = (int*)d_ws + o_counts;
    int*          startv  = (int*)d_ws + o_start;
    float*        recip   = (float*)d_ws + o_recip;
    int*          idx_ws  = (int*)d_ws + o_idx;
    int*          jloc    = (int*)d_ws + o_jloc;
    int*          voxid   = (int*)d_ws + o_voxid;
    unsigned int* gridT2  = (unsigned int*)((float*)d_ws + o_gridT);
    unsigned int* fTs32   = (unsigned int*)((float*)d_ws + o_fTs);

    // zero header + counts via our own kernel (keeps rocclr fills out of the graph)
    const int zero4 = (int)((64 + BR3) / 4);
    k_zero<<<(zero4 + 255) / 256, 256, 0, stream>>>((float4*)d_ws, zero4);

    const int BLK = 256;
    dim3 gRed(32, B);
    k_sums<<<gRed, BLK, 0, stream>>>(coords, ws_sums, N);
    k_maxrad<<<gRed, BLK, 0, stream>>>(coords, ws_sums, ws_max, N);

    dim3 gPts((N + BLK - 1) / BLK, B);
    k_points<<<gPts, BLK, 0, stream>>>(coords, ws_sums, ws_max, out_norm, idx_ws, jloc, counts, N);

    if (ws_size >= need && C == 64) {
        k_scan<<<dim3(B), 1024, 0, stream>>>(counts, startv, N);
        dim3 gT((N + 255) / 256, B);
        k_transpose_perm<<<gT, 1024, 0, stream>>>(feats, idx_ws, jloc, startv,
                                                  fTs32, voxid, N);
        const int nchunk = (N + CH - 1) / CH;
        dim3 gG((nchunk + 3) / 4, B);
        k_gather4<<<gG, 256, 0, stream>>>(fTs32, voxid, startv, gridT2, N, nchunk);
        dim3 gF(R3V / 64, B);
        k_fin<<<gF, 256, 0, stream>>>(gridT2, counts, out_grid);
    } else {
        const int tot = B * R3V;
        k_recip_fb<<<(tot + BLK - 1) / BLK, BLK, 0, stream>>>(counts, recip, tot);
        k_scatter_lds<<<dim3(BC), 1024, R3V * sizeof(float), stream>>>(
            feats, idx_ws, recip, out_grid, N, C);
    }
}